// Round 1
// baseline (2233.600 us; speedup 1.0000x reference)
//
#include <hip/hip_runtime.h>
#include <hip/hip_bf16.h>
#include <cstdint>
#include <cstddef>

#define M_DIM 8192
#define K_DIM 4096
#define N_DIM 16384

// ---- GEMM geometry: 256x256 block tile, BK=32, 4 LDS buffers, 8 waves ----
#define BM 256
#define BN 256
#define BK 32
#define NT (K_DIM / BK)      // 128 K-tiles
#define GX (N_DIM / BN)      // 64
#define GY (M_DIM / BM)      // 32
#define NWG (GX * GY)        // 2048 (divisible by 8 -> bijective XCD swizzle)
#define CPX (NWG / 8)        // 256 blocks per XCD chunk

typedef __attribute__((ext_vector_type(8))) short short8;
typedef __attribute__((ext_vector_type(4))) float floatx4;

// async global->LDS, 16B per lane. LDS dest must be wave-uniform base (+lane*16 by HW).
__device__ inline void gl2lds16(const void* g, void* l) {
  __builtin_amdgcn_global_load_lds(
      (const __attribute__((address_space(1))) void*)g,
      (__attribute__((address_space(3))) void*)l, 16, 0, 0);
}

// ---------------- Kernel 1: sum(|W|) in double ----------------
__global__ void abssum_kernel(const float* __restrict__ w, double* __restrict__ out) {
  size_t tid = (size_t)blockIdx.x * blockDim.x + threadIdx.x;
  size_t stride = (size_t)gridDim.x * blockDim.x;
  const float4* w4 = (const float4*)w;
  const size_t n4 = (size_t)N_DIM * K_DIM / 4;
  double s = 0.0;
  for (size_t i = tid; i < n4; i += stride) {
    float4 v = w4[i];
    s += (double)fabsf(v.x) + (double)fabsf(v.y) + (double)fabsf(v.z) + (double)fabsf(v.w);
  }
  #pragma unroll
  for (int off = 32; off > 0; off >>= 1) s += __shfl_down(s, off, 64);
  if ((threadIdx.x & 63) == 0) atomicAdd(out, s);
}

// ---------------- Kernel 2: ternarize W -> bf16 (as ushort bits) ----------------
__global__ void ternarize_kernel(const float* __restrict__ w, ushort* __restrict__ tw,
                                 const double* __restrict__ sum) {
  const float thr = (float)(0.5 * (*sum) / (double)((size_t)N_DIM * K_DIM));
  size_t i = ((size_t)blockIdx.x * blockDim.x + threadIdx.x) * 8;
  float4 a = *(const float4*)(w + i);
  float4 b = *(const float4*)(w + i + 4);
  float v[8] = {a.x, a.y, a.z, a.w, b.x, b.y, b.z, b.w};
  union { ushort u[8]; uint4 q; } o;
  #pragma unroll
  for (int j = 0; j < 8; j++) {
    float av = fabsf(v[j]);
    o.u[j] = (av >= thr) ? ((v[j] > 0.0f) ? (ushort)0x3F80 : (ushort)0xBF80) : (ushort)0;
  }
  *(uint4*)(tw + i) = o.q;
}

// ---------------- Kernel 3: cast x -> bf16 (RNE) ----------------
__device__ inline ushort f2bf(float f) {
  uint32_t u = __float_as_uint(f);
  return (ushort)((u + 0x7FFFu + ((u >> 16) & 1u)) >> 16);
}
__global__ void bf16cast_kernel(const float* __restrict__ x, ushort* __restrict__ xb) {
  size_t i = ((size_t)blockIdx.x * blockDim.x + threadIdx.x) * 8;
  float4 a = *(const float4*)(x + i);
  float4 b = *(const float4*)(x + i + 4);
  float v[8] = {a.x, a.y, a.z, a.w, b.x, b.y, b.z, b.w};
  union { ushort u[8]; uint4 q; } o;
  #pragma unroll
  for (int j = 0; j < 8; j++) o.u[j] = f2bf(v[j]);
  *(uint4*)(xb + i) = o.q;
}

// ---------------- Kernel 4: C[m,n] = sum_k A[m,k]*B[n,k] + bias[n] ----------------
// 256x256 tile, BK=32, 512 threads (8 waves: 2 m-halves x 4 n-quarters).
// Per wave: 128x64 output = acc[8][4] 16x16 frags.
// Pipeline: 4 LDS buffers (tile t in buf t&3), 2 phases per tile:
//   P1: 12x ds_read_b128 (all frags) || stage B(t+3) -> bar -> lgkm(0) -> 16 MFMA m0-3 -> bar
//   P2: stage A(t+4) -> vmcnt(10) [tail: 0] -> bar -> 16 MFMA m4-7 -> bar
// Counted vmcnt: after the wait, exactly 5 half-tile stages (10 loads) remain in flight.
// Release proof: all reads of buf[t&3] complete at P1's lgkm(0)+end-barrier, so
// A(t+4) (issued t.P2) and B(t+3) (issued (t... t'.P1 with t'=t+... 2 barriers later)
// never overwrite live data. Reads of tile t are guarded by (t-1).P2's vmcnt+barrier.
// LDS rows are 64 B -> frag reads hit 16B-slot (4*r16+quad)%8: even 8-way coverage,
// bank-conflict-free with NO swizzle, and global_load_lds stays linear.
__global__ __launch_bounds__(512, 2)
void gemm_bt_kernel(const ushort* __restrict__ A, const ushort* __restrict__ B,
                    const float* __restrict__ bias, float* __restrict__ C) {
  __shared__ __align__(16) ushort As[4][BM * BK];   // 64 KiB
  __shared__ __align__(16) ushort Bs[4][BN * BK];   // 64 KiB

  const int tid  = threadIdx.x;
  const int wave = tid >> 6;          // 0..7
  const int lane = tid & 63;
  const int wm   = wave >> 2;         // 0..1  (m half of the 256-row tile)
  const int wn   = wave & 3;          // 0..3  (n quarter of the 256-col tile)
  const int r16  = lane & 15;
  const int quad = lane >> 4;

  // T1: XCD-aware bijective swizzle (2048 % 8 == 0)
  const int flat = (int)(blockIdx.y * GX + blockIdx.x);
  const int swz  = (flat & 7) * CPX + (flat >> 3);
  const int bm   = swz / GX;
  const int bn   = swz % GX;

  // staging geometry: layer q in {0,1} covers rows [q*128, q*128+128);
  // wave stages 16 rows (1 KiB linear LDS): lane -> row (lane>>2), col (lane&3)*8.
  const int srow = wave * 16 + (lane >> 2);
  const int scol = (lane & 3) * 8;
  const ushort* pA0 = A + (size_t)(bm * BM + srow) * K_DIM + scol;
  const ushort* pA1 = pA0 + (size_t)128 * K_DIM;
  const ushort* pB0 = B + (size_t)(bn * BN + srow) * K_DIM + scol;
  const ushort* pB1 = pB0 + (size_t)128 * K_DIM;
  const int ldsw = wave * 16 * BK;    // wave-uniform LDS element offset

#define STAGE_A(T) do { const int _b = (T) & 3;                        \
    gl2lds16(pA0 + (size_t)(T) * BK, &As[_b][ldsw]);                   \
    gl2lds16(pA1 + (size_t)(T) * BK, &As[_b][128 * BK + ldsw]); } while (0)
#define STAGE_B(T) do { const int _b = (T) & 3;                        \
    gl2lds16(pB0 + (size_t)(T) * BK, &Bs[_b][ldsw]);                   \
    gl2lds16(pB1 + (size_t)(T) * BK, &Bs[_b][128 * BK + ldsw]); } while (0)

  floatx4 acc[8][4];
  #pragma unroll
  for (int m = 0; m < 8; m++)
    #pragma unroll
    for (int n = 0; n < 4; n++)
      acc[m][n] = (floatx4){0.f, 0.f, 0.f, 0.f};

  // prologue: tiles 0..2 fully + 3.A  => 14 loads in flight; wait for tile 0 (oldest 4)
  STAGE_A(0); STAGE_B(0);
  STAGE_A(1); STAGE_B(1);
  STAGE_A(2); STAGE_B(2);
  STAGE_A(3);
  asm volatile("s_waitcnt vmcnt(10)" ::: "memory");
  __builtin_amdgcn_s_barrier();

  const int aoff = (wm * 128 + r16) * BK + quad * 8;
  const int boff = (wn * 64  + r16) * BK + quad * 8;

  for (int t = 0; t < NT; ++t) {
    const int cb = t & 3;
    // ---------- phase 1 ----------
    short8 a[8], b[4];
    const ushort* aB = &As[cb][aoff];
    const ushort* bB = &Bs[cb][boff];
    #pragma unroll
    for (int m = 0; m < 8; ++m) a[m] = *(const short8*)(aB + m * 16 * BK);
    #pragma unroll
    for (int n = 0; n < 4; ++n) b[n] = *(const short8*)(bB + n * 16 * BK);
    if (t + 3 < NT) STAGE_B(t + 3);
    __builtin_amdgcn_s_barrier();
    asm volatile("s_waitcnt lgkmcnt(0)" ::: "memory");
    __builtin_amdgcn_sched_barrier(0);     // rule #18: pin MFMA after the lgkm wait
    __builtin_amdgcn_s_setprio(1);
    #pragma unroll
    for (int m = 0; m < 4; ++m)
      #pragma unroll
      for (int n = 0; n < 4; ++n)
        acc[m][n] = __builtin_amdgcn_mfma_f32_16x16x32_bf16(a[m], b[n], acc[m][n], 0, 0, 0);
    __builtin_amdgcn_s_setprio(0);
    __builtin_amdgcn_s_barrier();
    // ---------- phase 2 ----------
    if (t + 4 < NT) {
      STAGE_A(t + 4);
      asm volatile("s_waitcnt vmcnt(10)" ::: "memory");  // counted: never 0 in steady state
    } else {
      asm volatile("s_waitcnt vmcnt(0)" ::: "memory");   // tail drain (last 4 of 128 tiles)
    }
    __builtin_amdgcn_s_barrier();
    __builtin_amdgcn_s_setprio(1);
    #pragma unroll
    for (int m = 4; m < 8; ++m)
      #pragma unroll
      for (int n = 0; n < 4; ++n)
        acc[m][n] = __builtin_amdgcn_mfma_f32_16x16x32_bf16(a[m], b[n], acc[m][n], 0, 0, 0);
    __builtin_amdgcn_s_setprio(0);
    __builtin_amdgcn_s_barrier();
  }

  // epilogue: C/D layout col=lane&15, row=quad*4+reg (m89/m91-verified)
  const int crow = bm * BM + wm * 128 + quad * 4;
  const int ccol = bn * BN + wn * 64 + r16;
  #pragma unroll
  for (int n = 0; n < 4; ++n) {
    const int col = ccol + n * 16;
    const float bv = bias[col];
    #pragma unroll
    for (int m = 0; m < 8; ++m) {
      const size_t row0 = (size_t)(crow + m * 16);
      #pragma unroll
      for (int r = 0; r < 4; ++r)
        C[(row0 + r) * N_DIM + col] = acc[m][n][r] + bv;
    }
  }
#undef STAGE_A
#undef STAGE_B
}

extern "C" void kernel_launch(void* const* d_in, const int* in_sizes, int n_in,
                              void* d_out, int out_size, void* d_ws, size_t ws_size,
                              hipStream_t stream) {
  const float* x    = (const float*)d_in[0];   // [8192, 4096]
  const float* w    = (const float*)d_in[1];   // [16384, 4096]
  const float* bias = (const float*)d_in[2];   // [16384]
  float* out = (float*)d_out;                  // [8192, 16384]

  char* ws = (char*)d_ws;
  double* sum = (double*)ws;                                        // 8 B
  ushort* xb  = (ushort*)(ws + 256);                                // 64 MiB
  ushort* tw  = (ushort*)(ws + 256 + (size_t)M_DIM * K_DIM * 2);    // 128 MiB

  hipMemsetAsync(sum, 0, sizeof(double), stream);
  abssum_kernel<<<2048, 256, 0, stream>>>(w, sum);
  ternarize_kernel<<<(size_t)N_DIM * K_DIM / 8 / 256, 256, 0, stream>>>(w, tw, sum);
  bf16cast_kernel<<<(size_t)M_DIM * K_DIM / 8 / 256, 256, 0, stream>>>(x, xb);

  dim3 grid(GX, GY);
  gemm_bt_kernel<<<grid, 512, 0, stream>>>(xb, tw, bias, out);
}

// Round 2
// 1997.940 us; speedup vs baseline: 1.1180x; 1.1180x over previous
//
#include <hip/hip_runtime.h>
#include <hip/hip_bf16.h>
#include <cstdint>
#include <cstddef>

#define M_DIM 8192
#define K_DIM 4096
#define N_DIM 16384

// ---- GEMM geometry: 256x256 block tile, BK=32, 4 LDS buffers, 8 waves ----
#define BM 256
#define BN 256
#define BK 32
#define NT (K_DIM / BK)      // 128 K-tiles
#define GX (N_DIM / BN)      // 64
#define GY (M_DIM / BM)      // 32

typedef __attribute__((ext_vector_type(8))) short short8;
typedef __attribute__((ext_vector_type(4))) float floatx4;

// async global->LDS, 16B per lane. LDS dest must be wave-uniform base (+lane*16 by HW).
__device__ inline void gl2lds16(const void* g, void* l) {
  __builtin_amdgcn_global_load_lds(
      (const __attribute__((address_space(1))) void*)g,
      (__attribute__((address_space(3))) void*)l, 16, 0, 0);
}

// ---------------- Kernel 1: sum(|W|) in double ----------------
__global__ void abssum_kernel(const float* __restrict__ w, double* __restrict__ out) {
  size_t tid = (size_t)blockIdx.x * blockDim.x + threadIdx.x;
  size_t stride = (size_t)gridDim.x * blockDim.x;
  const float4* w4 = (const float4*)w;
  const size_t n4 = (size_t)N_DIM * K_DIM / 4;
  double s = 0.0;
  for (size_t i = tid; i < n4; i += stride) {
    float4 v = w4[i];
    s += (double)fabsf(v.x) + (double)fabsf(v.y) + (double)fabsf(v.z) + (double)fabsf(v.w);
  }
  #pragma unroll
  for (int off = 32; off > 0; off >>= 1) s += __shfl_down(s, off, 64);
  if ((threadIdx.x & 63) == 0) atomicAdd(out, s);
}

// ---------------- Kernel 2: ternarize W -> bf16 (as ushort bits) ----------------
__global__ void ternarize_kernel(const float* __restrict__ w, ushort* __restrict__ tw,
                                 const double* __restrict__ sum) {
  __shared__ float sthr;
  if (threadIdx.x == 0)
    sthr = (float)(0.5 * (*sum) / (double)((size_t)N_DIM * K_DIM));  // 1 fp64 div per block
  __syncthreads();
  const float thr = sthr;
  size_t i = ((size_t)blockIdx.x * blockDim.x + threadIdx.x) * 8;
  float4 a = *(const float4*)(w + i);
  float4 b = *(const float4*)(w + i + 4);
  float v[8] = {a.x, a.y, a.z, a.w, b.x, b.y, b.z, b.w};
  union { ushort u[8]; uint4 q; } o;
  #pragma unroll
  for (int j = 0; j < 8; j++) {
    float av = fabsf(v[j]);
    o.u[j] = (av >= thr) ? ((v[j] > 0.0f) ? (ushort)0x3F80 : (ushort)0xBF80) : (ushort)0;
  }
  *(uint4*)(tw + i) = o.q;
}

// ---------------- Kernel 3: cast x -> bf16 (RNE) ----------------
__device__ inline ushort f2bf(float f) {
  uint32_t u = __float_as_uint(f);
  return (ushort)((u + 0x7FFFu + ((u >> 16) & 1u)) >> 16);
}
__global__ void bf16cast_kernel(const float* __restrict__ x, ushort* __restrict__ xb) {
  size_t i = ((size_t)blockIdx.x * blockDim.x + threadIdx.x) * 8;
  float4 a = *(const float4*)(x + i);
  float4 b = *(const float4*)(x + i + 4);
  float v[8] = {a.x, a.y, a.z, a.w, b.x, b.y, b.z, b.w};
  union { ushort u[8]; uint4 q; } o;
  #pragma unroll
  for (int j = 0; j < 8; j++) o.u[j] = f2bf(v[j]);
  *(uint4*)(xb + i) = o.q;
}

// ---------------- Kernel 4: C[m,n] = sum_k A[m,k]*B[n,k] + bias[n] ----------------
// 256x256 tile, BK=32, 512 threads (8 waves), 4 LDS buffers, counted-vmcnt pipeline
// (sync skeleton verified round 1). Round-2 changes:
//  * LDS XOR-swizzle S(addr)=addr^((row&7)<<4): read-side XOR + inverse-permuted
//    per-lane GLOBAL source, LDS dest stays linear (rule #21 both-sides).
//    Kills the 8-lanes-per-16B-slot conflict (was 1.0e8 conflict cycles).
//  * Patch swizzle: 256 concurrent blocks = one 16bm x 16bn patch; XCD f&7 owns
//    an 8x4 sub-patch, all XCDs time-aligned on the same patch -> concurrent
//    panel sharing in L2/LLC (was: 1 row x 32 cols per XCD, B streamed 13x from HBM).
//  * Non-temporal C stores: keep the 512 MiB C stream from evicting A/B in LLC.
//  * lgkmcnt(4) before phase-1 MFMA (a4-7 still in flight), lgkmcnt(0) before phase-2.
__global__ __launch_bounds__(512, 2)
void gemm_bt_kernel(const ushort* __restrict__ A, const ushort* __restrict__ B,
                    const float* __restrict__ bias, float* __restrict__ C) {
  __shared__ __align__(128) ushort As[4][BM * BK];   // 64 KiB
  __shared__ __align__(128) ushort Bs[4][BN * BK];   // 64 KiB

  const int tid  = threadIdx.x;
  const int wave = tid >> 6;          // 0..7
  const int lane = tid & 63;
  const int wm   = wave >> 2;         // 0..1  (m half)
  const int wn   = wave & 3;          // 0..3  (n quarter)
  const int r16  = lane & 15;
  const int quad = lane >> 4;

  // Patch swizzle: f -> (xcd, patch, in-patch). Bijective: bm/bn bits reconstruct f.
  const int f  = (int)(blockIdx.y * GX + blockIdx.x);   // 0..2047
  const int xc = f & 7;              // XCD (HW round-robin by flat id)
  const int j  = f >> 3;             // 0..255 (sequential within XCD)
  const int p  = j >> 5;             // patch 0..7 (32 blocks/XCD/patch = resident set)
  const int k  = j & 31;
  const int pm = p >> 2, pn = p & 3; // patch grid 2 x 4 (of 16x16-block patches)
  const int bm = pm * 16 + ((xc >> 2) << 3) + (k & 7);   // [0,32)
  const int bn = pn * 16 + ((xc & 3) << 2) + (k >> 3);   // [0,64)

  // Staging: wave stages a 16-row x 64B chunk per layer, LDS dest linear (lane*16B).
  // Inverse swizzle on the GLOBAL source: lane l loads element (rr, q) such that
  // S(rr,q) = l*16, with S(r,q) = (r*64 + q*16) ^ ((r&7)<<4).  (verified l=0..16)
  const int bsw = ((lane >> 2) ^ (lane >> 4)) & 1;
  const int rr  = ((lane >> 3) << 1) | bsw;                       // row in chunk 0..15
  const int qb1 = ((lane >> 1) ^ (lane >> 3)) & 1;
  const int qb0 = (lane ^ (lane >> 2) ^ (lane >> 4)) & 1;
  const int qq  = (qb1 << 1) | qb0;                               // 16B slot 0..3
  const int srow = wave * 16 + rr;
  const int scol = qq * 8;
  const ushort* pA0 = A + (size_t)(bm * BM + srow) * K_DIM + scol;
  const ushort* pA1 = pA0 + (size_t)128 * K_DIM;
  const ushort* pB0 = B + (size_t)(bn * BN + srow) * K_DIM + scol;
  const ushort* pB1 = pB0 + (size_t)128 * K_DIM;
  const int ldsw = wave * 16 * BK;    // wave-uniform LDS element offset (linear dest)

#define STAGE_A(T) do { const int _b = (T) & 3;                        \
    gl2lds16(pA0 + (size_t)(T) * BK, &As[_b][ldsw]);                   \
    gl2lds16(pA1 + (size_t)(T) * BK, &As[_b][128 * BK + ldsw]); } while (0)
#define STAGE_B(T) do { const int _b = (T) & 3;                        \
    gl2lds16(pB0 + (size_t)(T) * BK, &Bs[_b][ldsw]);                   \
    gl2lds16(pB1 + (size_t)(T) * BK, &Bs[_b][128 * BK + ldsw]); } while (0)

  floatx4 acc[8][4];
  #pragma unroll
  for (int m = 0; m < 8; m++)
    #pragma unroll
    for (int n = 0; n < 4; n++)
      acc[m][n] = (floatx4){0.f, 0.f, 0.f, 0.f};

  // prologue: tiles 0..2 fully + 3.A => 14 loads in flight; wait 10 -> tile 0 ready
  STAGE_A(0); STAGE_B(0);
  STAGE_A(1); STAGE_B(1);
  STAGE_A(2); STAGE_B(2);
  STAGE_A(3);
  asm volatile("s_waitcnt vmcnt(10)" ::: "memory");
  __builtin_amdgcn_s_barrier();

  // Read-side swizzled byte offsets: inner = (r16*64 + quad*16) ^ ((r16&7)<<4),
  // then + m*1024 (A) / + n*1024 (B) folds into ds_read offset immediates.
  const int inner = ((r16 << 6) + (quad << 4)) ^ ((r16 & 7) << 4);
  const char* aBytes; const char* bBytes;

  for (int t = 0; t < NT; ++t) {
    const int cb = t & 3;
    aBytes = (const char*)(&As[cb][0]) + wm * 8192 + inner;
    bBytes = (const char*)(&Bs[cb][0]) + wn * 4096 + inner;
    // ---------- phase 1: all frag reads (order-pinned), stage B(t+3) ----------
    short8 a[8], b[4];
    #pragma unroll
    for (int m = 0; m < 4; ++m) a[m] = *(const short8*)(aBytes + m * 1024);
    #pragma unroll
    for (int n = 0; n < 4; ++n) b[n] = *(const short8*)(bBytes + n * 1024);
    __builtin_amdgcn_sched_barrier(0);     // pin group boundary for counted lgkm
    #pragma unroll
    for (int m = 4; m < 8; ++m) a[m] = *(const short8*)(aBytes + m * 1024);
    if (t + 3 < NT) STAGE_B(t + 3);
    __builtin_amdgcn_sched_barrier(0);
    __builtin_amdgcn_s_barrier();
    asm volatile("s_waitcnt lgkmcnt(4)" ::: "memory");  // a0-3,b0-3 done; a4-7 in flight
    __builtin_amdgcn_sched_barrier(0);     // rule #18
    __builtin_amdgcn_s_setprio(1);
    #pragma unroll
    for (int m = 0; m < 4; ++m)
      #pragma unroll
      for (int n = 0; n < 4; ++n)
        acc[m][n] = __builtin_amdgcn_mfma_f32_16x16x32_bf16(a[m], b[n], acc[m][n], 0, 0, 0);
    __builtin_amdgcn_s_setprio(0);
    __builtin_amdgcn_s_barrier();
    // ---------- phase 2: stage A(t+4), counted vmcnt, MFMA m4-7 ----------
    if (t + 4 < NT) {
      STAGE_A(t + 4);
      asm volatile("s_waitcnt vmcnt(10)" ::: "memory");  // never 0 in steady state
    } else {
      asm volatile("s_waitcnt vmcnt(0)" ::: "memory");   // tail drain
    }
    __builtin_amdgcn_s_barrier();
    asm volatile("s_waitcnt lgkmcnt(0)" ::: "memory");   // a4-7 (long since done)
    __builtin_amdgcn_sched_barrier(0);
    __builtin_amdgcn_s_setprio(1);
    #pragma unroll
    for (int m = 4; m < 8; ++m)
      #pragma unroll
      for (int n = 0; n < 4; ++n)
        acc[m][n] = __builtin_amdgcn_mfma_f32_16x16x32_bf16(a[m], b[n], acc[m][n], 0, 0, 0);
    __builtin_amdgcn_s_setprio(0);
    __builtin_amdgcn_s_barrier();
  }

  // epilogue: C/D layout col=lane&15, row=quad*4+reg (m89/m91-verified).
  // Non-temporal stores: C is write-once, keep it out of the LLC.
  const int crow = bm * BM + wm * 128 + quad * 4;
  const int ccol = bn * BN + wn * 64 + r16;
  #pragma unroll
  for (int n = 0; n < 4; ++n) {
    const int col = ccol + n * 16;
    const float bv = bias[col];
    #pragma unroll
    for (int m = 0; m < 8; ++m) {
      const size_t row0 = (size_t)(crow + m * 16);
      #pragma unroll
      for (int r = 0; r < 4; ++r)
        __builtin_nontemporal_store(acc[m][n][r] + bv, &C[(row0 + r) * N_DIM + col]);
    }
  }
#undef STAGE_A
#undef STAGE_B
}

extern "C" void kernel_launch(void* const* d_in, const int* in_sizes, int n_in,
                              void* d_out, int out_size, void* d_ws, size_t ws_size,
                              hipStream_t stream) {
  const float* x    = (const float*)d_in[0];   // [8192, 4096]
  const float* w    = (const float*)d_in[1];   // [16384, 4096]
  const float* bias = (const float*)d_in[2];   // [16384]
  float* out = (float*)d_out;                  // [8192, 16384]

  char* ws = (char*)d_ws;
  double* sum = (double*)ws;                                        // 8 B
  ushort* xb  = (ushort*)(ws + 256);                                // 64 MiB
  ushort* tw  = (ushort*)(ws + 256 + (size_t)M_DIM * K_DIM * 2);    // 128 MiB

  hipMemsetAsync(sum, 0, sizeof(double), stream);
  abssum_kernel<<<2048, 256, 0, stream>>>(w, sum);
  ternarize_kernel<<<(size_t)N_DIM * K_DIM / 8 / 256, 256, 0, stream>>>(w, tw, sum);
  bf16cast_kernel<<<(size_t)M_DIM * K_DIM / 8 / 256, 256, 0, stream>>>(x, xb);

  dim3 grid(GX, GY);
  gemm_bt_kernel<<<grid, 512, 0, stream>>>(xb, tw, bias, out);
}

// Round 4
// 1817.975 us; speedup vs baseline: 1.2286x; 1.0990x over previous
//
#include <hip/hip_runtime.h>
#include <hip/hip_bf16.h>
#include <cstdint>
#include <cstddef>

#define M_DIM 8192
#define K_DIM 4096
#define N_DIM 16384

// ---- GEMM geometry: 256x256 block tile, BK=32, 4 LDS buffers, 8 waves ----
#define BM 256
#define BN 256
#define BK 32
#define NT (K_DIM / BK)      // 128 K-tiles
#define GX (N_DIM / BN)      // 64
#define GY (M_DIM / BM)      // 32

typedef __attribute__((ext_vector_type(8))) short short8;
typedef __attribute__((ext_vector_type(4))) float floatx4;

// async global->LDS, 16B per lane. LDS dest must be wave-uniform base (+lane*16 by HW).
__device__ inline void gl2lds16(const void* g, void* l) {
  __builtin_amdgcn_global_load_lds(
      (const __attribute__((address_space(1))) void*)g,
      (__attribute__((address_space(3))) void*)l, 16, 0, 0);
}

// ---------------- Kernel 1a: per-block partial sum(|W|) (NO atomics) ----------------
// r2 post-mortem: 8192 serialized f64 atomicAdds to one address were the prime suspect
// for ~600us of non-GEMM time. Two-stage reduction instead.
__global__ void abssum_partial(const float* __restrict__ w, double* __restrict__ part) {
  size_t tid = (size_t)blockIdx.x * blockDim.x + threadIdx.x;
  size_t stride = (size_t)gridDim.x * blockDim.x;
  const float4* w4 = (const float4*)w;
  const size_t n4 = (size_t)N_DIM * K_DIM / 4;
  double s = 0.0;
  for (size_t i = tid; i < n4; i += stride) {
    float4 v = w4[i];
    s += (double)fabsf(v.x) + (double)fabsf(v.y) + (double)fabsf(v.z) + (double)fabsf(v.w);
  }
  #pragma unroll
  for (int off = 32; off > 0; off >>= 1) s += __shfl_down(s, off, 64);
  __shared__ double sred[4];
  if ((threadIdx.x & 63) == 0) sred[threadIdx.x >> 6] = s;
  __syncthreads();
  if (threadIdx.x == 0) part[blockIdx.x] = sred[0] + sred[1] + sred[2] + sred[3];
}

// ---------------- Kernel 1b: final reduce of 2048 partials ----------------
__global__ void abssum_final(const double* __restrict__ part, double* __restrict__ sum) {
  const int tid = threadIdx.x;
  double s = 0.0;
  #pragma unroll
  for (int k = 0; k < 8; ++k) s += part[tid + k * 256];
  #pragma unroll
  for (int off = 32; off > 0; off >>= 1) s += __shfl_down(s, off, 64);
  __shared__ double sred[4];
  if ((tid & 63) == 0) sred[tid >> 6] = s;
  __syncthreads();
  if (tid == 0) *sum = sred[0] + sred[1] + sred[2] + sred[3];
}

// ---------------- Kernel 2: ternarize W -> bf16 (as ushort bits) ----------------
__global__ void ternarize_kernel(const float* __restrict__ w, ushort* __restrict__ tw,
                                 const double* __restrict__ sum) {
  __shared__ float sthr;
  if (threadIdx.x == 0)
    sthr = (float)(0.5 * (*sum) / (double)((size_t)N_DIM * K_DIM));
  __syncthreads();
  const float thr = sthr;
  size_t i = ((size_t)blockIdx.x * blockDim.x + threadIdx.x) * 8;
  float4 a = *(const float4*)(w + i);
  float4 b = *(const float4*)(w + i + 4);
  float v[8] = {a.x, a.y, a.z, a.w, b.x, b.y, b.z, b.w};
  union { ushort u[8]; uint4 q; } o;
  #pragma unroll
  for (int j = 0; j < 8; j++) {
    float av = fabsf(v[j]);
    o.u[j] = (av >= thr) ? ((v[j] > 0.0f) ? (ushort)0x3F80 : (ushort)0xBF80) : (ushort)0;
  }
  *(uint4*)(tw + i) = o.q;
}

// ---------------- Kernel 3: cast x -> bf16 (RNE) ----------------
__device__ inline ushort f2bf(float f) {
  uint32_t u = __float_as_uint(f);
  return (ushort)((u + 0x7FFFu + ((u >> 16) & 1u)) >> 16);
}
__global__ void bf16cast_kernel(const float* __restrict__ x, ushort* __restrict__ xb) {
  size_t i = ((size_t)blockIdx.x * blockDim.x + threadIdx.x) * 8;
  float4 a = *(const float4*)(x + i);
  float4 b = *(const float4*)(x + i + 4);
  float v[8] = {a.x, a.y, a.z, a.w, b.x, b.y, b.z, b.w};
  union { ushort u[8]; uint4 q; } o;
  #pragma unroll
  for (int j = 0; j < 8; j++) o.u[j] = f2bf(v[j]);
  *(uint4*)(xb + i) = o.q;
}

// ---------------- Kernel 4: C[m,n] = sum_k A[m,k]*B[n,k] + bias[n] ----------------
// Round-3 restructure (same 4-buffer/vmcnt(10) ledger, verified r1/r2; reads moved):
//   P1: STAGE_B(t+3); lgkm(0) [al(t),b(t) from prev P2]; issue ah(t) reads;
//       MFMA1 (m0-3) overlaps ah reads; lgkm(0); barrier(ii)
//   P2: STAGE_A(t+4); vmcnt(10); barrier(iii)  [ledger: A/B(t+1) landed];
//       issue al(t+1)+b(t+1) reads (b ping-pong, unroll-by-2); MFMA2 (m4-7, no wait)
// 2 barriers/tile (was 4). Write-after-read safety of dropped barriers re-derived:
//   STAGE_B(t+3) hits buf (t-1)&3; those reads completed before (ii) of t-1, and the
//   stage is issued after (iii) of t-1. STAGE_A(t+4) hits buf t&3; al/ah(t) reads
//   complete before (ii) of t, stage issued after (ii). Reads(t+1) from buf (t+1)&3
//   are valid after (iii) [vmcnt(10) forces A(t+1),B(t+1) complete]; next write to
//   that buf (A(t+5)) is issued after (ii) of t+1, by which time reads completed.
__global__ __launch_bounds__(512, 2)
void gemm_bt_kernel(const ushort* __restrict__ A, const ushort* __restrict__ B,
                    const float* __restrict__ bias, float* __restrict__ C) {
  __shared__ __align__(128) ushort As[4][BM * BK];   // 64 KiB
  __shared__ __align__(128) ushort Bs[4][BN * BK];   // 64 KiB

  const int tid  = threadIdx.x;
  const int wave = tid >> 6;          // 0..7
  const int lane = tid & 63;
  const int wm   = wave >> 2;         // 0..1  (m half)
  const int wn   = wave & 3;          // 0..3  (n quarter)
  const int r16  = lane & 15;
  const int quad = lane >> 4;

  // Patch swizzle (r2-verified): 256 concurrent blocks share one 16bm x 16bn patch.
  const int f  = (int)(blockIdx.y * GX + blockIdx.x);   // 0..2047
  const int xc = f & 7;
  const int j  = f >> 3;
  const int p  = j >> 5;
  const int k  = j & 31;
  const int pm = p >> 2, pn = p & 3;
  const int bm = pm * 16 + ((xc >> 2) << 3) + (k & 7);   // [0,32)
  const int bn = pn * 16 + ((xc & 3) << 2) + (k >> 3);   // [0,64)

  // Staging addressing (r2-verified, unchanged).
  const int bsw = ((lane >> 2) ^ (lane >> 4)) & 1;
  const int rr  = ((lane >> 3) << 1) | bsw;
  const int qb1 = ((lane >> 1) ^ (lane >> 3)) & 1;
  const int qb0 = (lane ^ (lane >> 2) ^ (lane >> 4)) & 1;
  const int qq  = (qb1 << 1) | qb0;
  const int srow = wave * 16 + rr;
  const int scol = qq * 8;
  const ushort* pA0 = A + (size_t)(bm * BM + srow) * K_DIM + scol;
  const ushort* pA1 = pA0 + (size_t)128 * K_DIM;
  const ushort* pB0 = B + (size_t)(bn * BN + srow) * K_DIM + scol;
  const ushort* pB1 = pB0 + (size_t)128 * K_DIM;
  const int ldsw = wave * 16 * BK;

#define STAGE_A(T) do { const int _b = (T) & 3;                        \
    gl2lds16(pA0 + (size_t)(T) * BK, &As[_b][ldsw]);                   \
    gl2lds16(pA1 + (size_t)(T) * BK, &As[_b][128 * BK + ldsw]); } while (0)
#define STAGE_B(T) do { const int _b = (T) & 3;                        \
    gl2lds16(pB0 + (size_t)(T) * BK, &Bs[_b][ldsw]);                   \
    gl2lds16(pB1 + (size_t)(T) * BK, &Bs[_b][128 * BK + ldsw]); } while (0)

  floatx4 acc[8][4];
  #pragma unroll
  for (int m = 0; m < 8; m++)
    #pragma unroll
    for (int n = 0; n < 4; n++)
      acc[m][n] = (floatx4){0.f, 0.f, 0.f, 0.f};

  // Read-side swizzled byte offset (r2-verified).
  const int inner = ((r16 << 6) + (quad << 4)) ^ ((r16 & 7) << 4);
#define ABYTES(T) ((const char*)(&As[(T) & 3][0]) + wm * 8192 + inner)
#define BBYTES(T) ((const char*)(&Bs[(T) & 3][0]) + wn * 4096 + inner)

  short8 al[4], ah[4], bA[4], bB[4];   // b ping-pong: even tiles consume bA, odd bB

  // prologue: tiles 0..2 fully + 3.A => 14 loads; vmcnt(10) -> tile 0 ready
  STAGE_A(0); STAGE_B(0);
  STAGE_A(1); STAGE_B(1);
  STAGE_A(2); STAGE_B(2);
  STAGE_A(3);
  asm volatile("s_waitcnt vmcnt(10)" ::: "memory");
  __builtin_amdgcn_s_barrier();
  {
    const char* aB0 = ABYTES(0);
    const char* bB0 = BBYTES(0);
    #pragma unroll
    for (int m = 0; m < 4; ++m) al[m] = *(const short8*)(aB0 + m * 1024);
    #pragma unroll
    for (int n = 0; n < 4; ++n) bA[n] = *(const short8*)(bB0 + n * 1024);
  }

#define ONE_TILE(T, bcur, bnxt) do {                                               \
    if ((T) + 3 < NT) STAGE_B((T) + 3);                                            \
    asm volatile("s_waitcnt lgkmcnt(0)" ::: "memory"); /* al(T), bcur(T) ready */  \
    __builtin_amdgcn_sched_barrier(0);                                             \
    { const char* _aB = ABYTES(T);                                                 \
      _Pragma("unroll")                                                            \
      for (int m = 0; m < 4; ++m)                                                  \
        ah[m] = *(const short8*)(_aB + (4 + m) * 1024); }                          \
    __builtin_amdgcn_sched_barrier(0);  /* pin: ah reads issue BEFORE MFMA1 */     \
    __builtin_amdgcn_s_setprio(1);                                                 \
    _Pragma("unroll")                                                              \
    for (int m = 0; m < 4; ++m)                                                    \
      _Pragma("unroll")                                                            \
      for (int n = 0; n < 4; ++n)                                                  \
        acc[m][n] = __builtin_amdgcn_mfma_f32_16x16x32_bf16(al[m], bcur[n], acc[m][n], 0, 0, 0); \
    __builtin_amdgcn_s_setprio(0);                                                 \
    asm volatile("s_waitcnt lgkmcnt(0)" ::: "memory");  /* ah done (had MFMA1) */  \
    __builtin_amdgcn_s_barrier();                       /* (ii) */                 \
    if ((T) + 4 < NT) {                                                            \
      STAGE_A((T) + 4);                                                            \
      asm volatile("s_waitcnt vmcnt(10)" ::: "memory"); /* counted, never 0 */     \
    } else {                                                                       \
      asm volatile("s_waitcnt vmcnt(0)" ::: "memory");  /* tail drain */           \
    }                                                                              \
    __builtin_amdgcn_s_barrier();                       /* (iii) */                \
    if ((T) + 1 < NT) {                                                            \
      const char* _aB = ABYTES((T) + 1); const char* _bB = BBYTES((T) + 1);        \
      _Pragma("unroll")                                                            \
      for (int m = 0; m < 4; ++m) al[m] = *(const short8*)(_aB + m * 1024);        \
      _Pragma("unroll")                                                            \
      for (int n = 0; n < 4; ++n) bnxt[n] = *(const short8*)(_bB + n * 1024);      \
    }                                                                              \
    __builtin_amdgcn_sched_barrier(0);  /* pin: t+1 reads issue BEFORE MFMA2 */    \
    __builtin_amdgcn_s_setprio(1);                                                 \
    _Pragma("unroll")                                                              \
    for (int m = 0; m < 4; ++m)                                                    \
      _Pragma("unroll")                                                            \
      for (int n = 0; n < 4; ++n)                                                  \
        acc[4 + m][n] = __builtin_amdgcn_mfma_f32_16x16x32_bf16(ah[m], bcur[n], acc[4 + m][n], 0, 0, 0); \
    __builtin_amdgcn_s_setprio(0);                                                 \
  } while (0)

  for (int t0 = 0; t0 < NT; t0 += 2) {
    ONE_TILE(t0, bA, bB);
    ONE_TILE(t0 + 1, bB, bA);
  }

  // epilogue: C/D layout col=lane&15, row=quad*4+reg (m89/m91-verified), NT stores.
  const int crow = bm * BM + wm * 128 + quad * 4;
  const int ccol = bn * BN + wn * 64 + r16;
  #pragma unroll
  for (int n = 0; n < 4; ++n) {
    const int col = ccol + n * 16;
    const float bv = bias[col];
    #pragma unroll
    for (int m = 0; m < 8; ++m) {
      const size_t row0 = (size_t)(crow + m * 16);
      #pragma unroll
      for (int r = 0; r < 4; ++r)
        __builtin_nontemporal_store(acc[m][n][r] + bv, &C[(row0 + r) * N_DIM + col]);
    }
  }
#undef ONE_TILE
#undef ABYTES
#undef BBYTES
#undef STAGE_A
#undef STAGE_B
}

extern "C" void kernel_launch(void* const* d_in, const int* in_sizes, int n_in,
                              void* d_out, int out_size, void* d_ws, size_t ws_size,
                              hipStream_t stream) {
  const float* x    = (const float*)d_in[0];   // [8192, 4096]
  const float* w    = (const float*)d_in[1];   // [16384, 4096]
  const float* bias = (const float*)d_in[2];   // [16384]
  float* out = (float*)d_out;                  // [8192, 16384]

  char* ws = (char*)d_ws;
  double* sum  = (double*)ws;                                       // 8 B
  double* part = (double*)(ws + 1024);                              // 16 KiB (2048 doubles)
  ushort* xb   = (ushort*)(ws + 32768);                             // 64 MiB
  ushort* tw   = (ushort*)(ws + 32768 + (size_t)M_DIM * K_DIM * 2); // 128 MiB

  abssum_partial<<<2048, 256, 0, stream>>>(w, part);
  abssum_final<<<1, 256, 0, stream>>>(part, sum);
  ternarize_kernel<<<(size_t)N_DIM * K_DIM / 8 / 256, 256, 0, stream>>>(w, tw, sum);
  bf16cast_kernel<<<(size_t)M_DIM * K_DIM / 8 / 256, 256, 0, stream>>>(x, xb);

  dim3 grid(GX, GY);
  gemm_bt_kernel<<<grid, 512, 0, stream>>>(xb, tw, bias, out);
}